// Round 8
// baseline (166.226 us; speedup 1.0000x reference)
//
#include <hip/hip_runtime.h>

// FK_Velocity_Loss: pos_loss = vel_loss = mean((out_fk - gt_fk)^2)
// (gt_prev_pose cancels exactly: (o - p) - (g - p) = o - g)
//
// R8: clean test of the coalescing hypothesis, all prior confounds removed:
//  - staging via global_load_lds width=16 (zero staging VGPRs -> no spill)
//  - per-wave double-buffered LDS, NO barriers; counted s_waitcnt vmcnt(8)
//  - both-sides XOR swizzle (linear LDS dest + pre-swizzled GLOBAL source,
//    same XOR on readback) -> conflict-free ds_read_b128 (2 lanes/bank)
//  - compute unchanged: DPP quad-broadcast mat-vec (VALU-only)
//  - grid 1250 x 128thr, 32KB LDS/block -> 5 blocks/CU, all co-resident
//  - finalize fused via last-block-done ticket (proven in R6)

#define N_CHAINS 800000
#define BLOCK 128                        // 2 waves
#define BLOCKS 1250
#define ITERS 20                         // 16 chains per wave-window, exact:
                                         // 1250*2*20*16 = 800000
#define MEAN_DIV (400000.0 * 2.0 * 3.0)

typedef const __attribute__((address_space(1))) void gv_t;
typedef __attribute__((address_space(3))) void lv_t;

// Broadcast lane (quad_base + I) across the quad. DPP quad_perm, VALU-only.
template <int I>
__device__ __forceinline__ float qb(float x) {
    return __builtin_bit_cast(float,
        __builtin_amdgcn_mov_dpp(__builtin_bit_cast(int, x),
                                 I | (I << 2) | (I << 4) | (I << 6),
                                 0xF, 0xF, true));
}

// Lane holds row k of M0..M3. Returns component k of (M0*M1*M2*M3)[:,3],
// right-to-left: v = M3[:,3]; v = M2*v; v = M1*v; v = M0*v.
__device__ __forceinline__ float fk_elem(float4 m0, float4 m1, float4 m2, float4 m3) {
    float v = m3.w;
    float v0, v1, v2, v3;
    v0 = qb<0>(v); v1 = qb<1>(v); v2 = qb<2>(v); v3 = qb<3>(v);
    v = m2.x * v0 + m2.y * v1 + m2.z * v2 + m2.w * v3;
    v0 = qb<0>(v); v1 = qb<1>(v); v2 = qb<2>(v); v3 = qb<3>(v);
    v = m1.x * v0 + m1.y * v1 + m1.z * v2 + m1.w * v3;
    v0 = qb<0>(v); v1 = qb<1>(v); v2 = qb<2>(v); v3 = qb<3>(v);
    v = m0.x * v0 + m0.y * v1 + m0.z * v2 + m0.w * v3;
    return v;
}

__global__ __launch_bounds__(BLOCK) void fk_loss_kernel(const float4* __restrict__ o4,
                                                        const float4* __restrict__ g4,
                                                        unsigned* __restrict__ counter,
                                                        float* __restrict__ partial,
                                                        float* __restrict__ out) {
    __shared__ float4 lds[2][2][2][256];   // [wave][buf][o|g][16 chains x 16 f4] = 32KB
    const int wid  = threadIdx.x >> 6;
    const int lane = threadIdx.x & 63;
    const int q = lane >> 2;               // chain within window, 0..15
    const int k = lane & 3;                // matrix row
    const int w = blockIdx.x * 2 + wid;    // wave id, 0..2499

    // Pre-swizzled per-lane global source for the 4 staging instrs per array:
    // LDS slot p (linear, forced by global_load_lds) holds G[p ^ ((p>>4)&7)].
    int soff[4];
#pragma unroll
    for (int t = 0; t < 4; ++t) {
        const int p = t * 64 + lane;
        soff[t] = p ^ ((p >> 4) & 7);
    }

    // stage window win into buf: 8 x global_load_lds dwordx4 (1KB/instr/wave)
    auto stage = [&](int buf, int win) {
        const size_t base = (size_t)win * 256;
#pragma unroll
        for (int t = 0; t < 4; ++t) {
            __builtin_amdgcn_global_load_lds((gv_t*)(o4 + base + soff[t]),
                                             (lv_t*)&lds[wid][buf][0][t * 64], 16, 0, 0);
            __builtin_amdgcn_global_load_lds((gv_t*)(g4 + base + soff[t]),
                                             (lv_t*)&lds[wid][buf][1][t * 64], 16, 0, 0);
        }
    };

    const int win0 = w * ITERS;
    stage(0, win0);

    // Readback indices: want G-chain float4 (q*16 + j*4 + k); it sits at LDS
    // index (q*16 + j*4 + k) ^ (q&7). Conflict-free: 2 lanes/bank per read.
    const int xq = q & 7;
    const int i0 = q * 16 + k;
    const int ix0 = (i0)      ^ xq, ix1 = (i0 + 4)  ^ xq;
    const int ix2 = (i0 + 8)  ^ xq, ix3 = (i0 + 12) ^ xq;

    float ss = 0.0f;
#pragma unroll 1
    for (int it = 0; it < ITERS; ++it) {
        const int b = it & 1;
        if (it + 1 < ITERS) {
            stage(b ^ 1, win0 + it + 1);
            asm volatile("s_waitcnt vmcnt(8)" ::: "memory");  // prev 8 landed,
        } else {                                              // next 8 in flight
            asm volatile("s_waitcnt vmcnt(0)" ::: "memory");
        }
        const float4* Lo = lds[wid][b][0];
        const float4* Lg = lds[wid][b][1];
        float4 mo0 = Lo[ix0], mo1 = Lo[ix1], mo2 = Lo[ix2], mo3 = Lo[ix3];
        float4 mg0 = Lg[ix0], mg1 = Lg[ix1], mg2 = Lg[ix2], mg3 = Lg[ix3];
        float fo = fk_elem(mo0, mo1, mo2, mo3);
        float fg = fk_elem(mg0, mg1, mg2, mg3);
        float d = fo - fg;
        if (k < 3) ss += d * d;
    }

    // wave shuffle reduce -> block reduce -> partial store + ticket
#pragma unroll
    for (int off = 32; off > 0; off >>= 1) ss += __shfl_down(ss, off, 64);
    __shared__ float part[2];
    __shared__ bool amlast;
    if (lane == 0) part[wid] = ss;
    __syncthreads();
    if (threadIdx.x == 0) {
        float bsum = part[0] + part[1];
        __hip_atomic_store(&partial[blockIdx.x], bsum, __ATOMIC_RELEASE,
                           __HIP_MEMORY_SCOPE_AGENT);
        unsigned prev = __hip_atomic_fetch_add(counter, 1u, __ATOMIC_ACQ_REL,
                                               __HIP_MEMORY_SCOPE_AGENT);
        amlast = (prev == BLOCKS - 1);
    }
    __syncthreads();

    if (amlast) {  // exactly one block, after all partials are visible
        double s = 0.0;
        for (int i = threadIdx.x; i < BLOCKS; i += BLOCK)
            s += (double)__hip_atomic_load(&partial[i], __ATOMIC_ACQUIRE,
                                           __HIP_MEMORY_SCOPE_AGENT);
        __shared__ double dpart[2];
#pragma unroll
        for (int off = 32; off > 0; off >>= 1) s += __shfl_down(s, off, 64);
        if ((threadIdx.x & 63) == 0) dpart[threadIdx.x >> 6] = s;
        __syncthreads();
        if (threadIdx.x == 0) {
            double bsum = dpart[0] + dpart[1];
            float v = (float)(bsum / MEAN_DIV);
            out[0] = v;  // pos_loss
            out[1] = v;  // vel_loss (identical: gt_prev cancels)
        }
    }
}

extern "C" void kernel_launch(void* const* d_in, const int* in_sizes, int n_in,
                              void* d_out, int out_size, void* d_ws, size_t ws_size,
                              hipStream_t stream) {
    const float4* output_pose = (const float4*)d_in[0];
    const float4* gt_pose     = (const float4*)d_in[1];
    // d_in[2] (gt_prev_pose) and d_in[3] (gt_pos) are not needed.
    float* out = (float*)d_out;
    unsigned* counter = (unsigned*)d_ws;              // 4 B, zeroed below
    float* partial = (float*)((char*)d_ws + 512);     // BLOCKS floats

    hipMemsetAsync(counter, 0, sizeof(unsigned), stream);   // capturable
    fk_loss_kernel<<<BLOCKS, BLOCK, 0, stream>>>(output_pose, gt_pose,
                                                 counter, partial, out);
}